// Round 7
// baseline (745.808 us; speedup 1.0000x reference)
//
#include <hip/hip_runtime.h>

typedef __attribute__((ext_vector_type(8))) short short8;
typedef __attribute__((ext_vector_type(4))) float f32x4;
typedef __attribute__((ext_vector_type(4))) unsigned int u32x4;
typedef __attribute__((ext_vector_type(2))) unsigned int u32x2;
typedef __attribute__((ext_vector_type(4))) unsigned short u16x4;

#define NHEADS 16
#define DHEAD 64
#define SEQ 2048
#define BATCH 4
#define HD 1024
#define MTOT 8192  // BATCH*SEQ

// RNE f32->bf16 (cold paths)
static __device__ __forceinline__ unsigned short f2b(float x) {
  unsigned u = __builtin_bit_cast(unsigned, x);
  u += 0x7fffu + ((u >> 16) & 1u);
  return (unsigned short)(u >> 16);
}

// round-half-up pack of two f32 -> bf16x2 (<=0.5 ulp, 4 insts; hot paths)
static __device__ __forceinline__ unsigned pk2h(float lo, float hi) {
  unsigned a = __builtin_bit_cast(unsigned, lo) + 0x8000u;
  unsigned b = __builtin_bit_cast(unsigned, hi) + 0x8000u;
  return (a >> 16) | (b & 0xffff0000u);
}

// async global -> LDS, 16B per lane. LDS dst = wave-uniform base + lane*16.
static __device__ __forceinline__ void gll16(const void* g, void* l) {
  __builtin_amdgcn_global_load_lds(
      (const __attribute__((address_space(1))) unsigned int*)g,
      (__attribute__((address_space(3))) unsigned int*)l, 16, 0, 0);
}

// ---------------- f32 -> bf16 conversion (hidden states) ----------------
__global__ void cvt_bf16(const float* __restrict__ src,
                         unsigned short* __restrict__ dst, int n4) {
  int i = blockIdx.x * blockDim.x + threadIdx.x;
  if (i < n4) {
    f32x4 v = ((const f32x4*)src)[i];
    u16x4 o;
    o[0] = f2b(v[0]); o[1] = f2b(v[1]); o[2] = f2b(v[2]); o[3] = f2b(v[3]);
    ((u16x4*)dst)[i] = o;
  }
}

// ---- combined prep: Wq/Wk/Wv -> bf16, wmask = bf16(exp(mask)) ----
#define WQ4 (HD * HD / 4)   // 262144 vec4s per weight matrix
__global__ void prep(const float* __restrict__ Wq, const float* __restrict__ Wk,
                     const float* __restrict__ Wv, const float* __restrict__ mask,
                     unsigned short* __restrict__ Wb,
                     unsigned short* __restrict__ Wm) {
  int i = blockIdx.x * blockDim.x + threadIdx.x;
  if (i < 3 * WQ4) {
    int rg = i / WQ4;
    int idx = i - rg * WQ4;
    const float* src = (rg == 0) ? Wq : (rg == 1) ? Wk : Wv;
    f32x4 v = ((const f32x4*)src)[idx];
    u16x4 o;
    o[0] = f2b(v[0]); o[1] = f2b(v[1]); o[2] = f2b(v[2]); o[3] = f2b(v[3]);
    ((u16x4*)(Wb + (size_t)rg * HD * HD))[idx] = o;
  } else {
    int j = i - 3 * WQ4;            // 0..2047 vec4s of mask
    f32x4 v = ((const f32x4*)mask)[j];
    u16x4 o;
    o[0] = f2b(__expf(v[0])); o[1] = f2b(__expf(v[1]));
    o[2] = f2b(__expf(v[2])); o[3] = f2b(__expf(v[3]));
    ((u16x4*)Wm)[j] = o;
  }
}

// ---------------- fused QKV GEMM + bias + rotary + scale/mask folds --------
// X: [8192][1024] bf16, W: [3][1024][1024] bf16.
// Q out: rotary * 0.125*log2(e), [B,NH,S,D] bf16.  K out: rotary, same layout.
// V out: transposed [B,NH,D,S'] bf16, columns s PERMUTED within 32-blocks
//        (s = u*16+a*4+r -> s' = a*8+u*4+r) and scaled by exp(mask[b][s]).
// BK=64 k-loop (16 steps): halves latency-exposed barriers vs BK=32.
// Gather-side XOR swizzle (chunk ^= row&7) keeps LDS reads conflict-free at
// 128-B row stride.  __launch_bounds__(256,4) targets <=128 VGPR (4 w/SIMD).
__global__ __launch_bounds__(256, 4) void qkv_gemm(
    const unsigned short* __restrict__ X,
    const unsigned short* __restrict__ Wall,
    const float* __restrict__ bq, const float* __restrict__ bk,
    const float* __restrict__ bv,
    const float* __restrict__ rel,          // [2048][64] f32
    const float* __restrict__ mask,         // [4][2048] f32
    unsigned short* __restrict__ Qo,
    unsigned short* __restrict__ Ko,
    unsigned short* __restrict__ Vt) {
  __shared__ __align__(16) unsigned short As[128 * 64];
  __shared__ __align__(16) unsigned short Bs[128 * 64];

  const int t = threadIdx.x;
  const int lane = t & 63;
  const int w = t >> 6;

  // XCD swizzle: pin each W panel (by,bz) to one XCD; bx fastest within panel.
  const int n = blockIdx.x;            // 0..1535
  const int xcd = n & 7;
  const int li = n >> 3;               // 0..191
  const int pp = xcd * 3 + (li >> 6);  // 0..23 W-panel id
  const int bx = li & 63;
  const int by = pp & 7;
  const int bz = pp >> 3;              // 0=Q 1=K 2=V

  const unsigned short* W = Wall + (size_t)bz * HD * HD;
  const int m0 = bx * 128;
  const int n0 = by * 128;

  f32x4 acc[4][4];
  for (int i = 0; i < 4; i++)
    for (int j = 0; j < 4; j++) acc[i][j] = (f32x4){0.f, 0.f, 0.f, 0.f};

  const int wm = (w & 1) * 64;
  const int wn = (w >> 1) * 64;
  const int cl = lane & 15;
  const int qd = lane >> 4;

  for (int k0 = 0; k0 < HD; k0 += 64) {
    __syncthreads();
    // stage 128x64 A and B tiles; lane -> row r0+(lane>>3), gathers global
    // chunk (lane&7)^(r&7) so LDS slot s at row r holds global chunk s^(r&7)
#pragma unroll
    for (int j = 0; j < 4; j++) {
      int r0 = w * 32 + j * 8;
      int r = r0 + (lane >> 3);
      int cg = (((lane & 7) ^ (r & 7)) << 3);
      gll16(X + (size_t)(m0 + r) * HD + k0 + cg, As + r0 * 64);
      gll16(W + (size_t)(n0 + r) * HD + k0 + cg, Bs + r0 * 64);
    }
    __syncthreads();

#pragma unroll
    for (int ks = 0; ks < 2; ks++) {
      const int cc = ks * 4 + qd;
      short8 af[4], bf[4];
#pragma unroll
      for (int i = 0; i < 4; i++) {
        int r = wm + i * 16 + cl;
        af[i] = *(const short8*)(As + r * 64 + ((cc ^ (r & 7)) << 3));
      }
#pragma unroll
      for (int j = 0; j < 4; j++) {
        int r = wn + j * 16 + cl;
        bf[j] = *(const short8*)(Bs + r * 64 + ((cc ^ (r & 7)) << 3));
      }
      if (bz < 2) {
        // transposed: acc[i][j] = D[n(feature)][m(s)]
#pragma unroll
        for (int i = 0; i < 4; i++)
#pragma unroll
          for (int j = 0; j < 4; j++)
            acc[i][j] = __builtin_amdgcn_mfma_f32_16x16x32_bf16(bf[j], af[i],
                                                                acc[i][j], 0, 0, 0);
      } else {
        // normal: acc[i][j] = D[m(s)][n(feature)]
#pragma unroll
        for (int i = 0; i < 4; i++)
#pragma unroll
          for (int j = 0; j < 4; j++)
            acc[i][j] = __builtin_amdgcn_mfma_f32_16x16x32_bf16(af[i], bf[j],
                                                                acc[i][j], 0, 0, 0);
      }
    }
  }

  // ---- epilogue ----
  if (bz == 2) {
    const int hh = (n0 + wn) >> 6;
#pragma unroll
    for (int i = 0; i < 4; i++) {
      int mb = m0 + wm + i * 16 + qd * 4;
      int bb = mb >> 11, ssb = mb & (SEQ - 1);
      f32x4 mk = *(const f32x4*)(mask + bb * SEQ + ssb);
      f32x4 w4;
#pragma unroll
      for (int r = 0; r < 4; r++) w4[r] = __expf(mk[r]);
      int colp = (ssb & ~31) | ((ssb & 12) << 1) | (((ssb >> 4) & 1) << 2);
#pragma unroll
      for (int j = 0; j < 4; j++) {
        int nn = n0 + wn + j * 16 + cl;
        int dd = j * 16 + cl;
        float bn = bv[nn];
        u32x2 pk;
        pk[0] = pk2h((acc[i][j][0] + bn) * w4[0], (acc[i][j][1] + bn) * w4[1]);
        pk[1] = pk2h((acc[i][j][2] + bn) * w4[2], (acc[i][j][3] + bn) * w4[3]);
        *(u32x2*)(Vt + ((size_t)((bb * NHEADS + hh) * DHEAD + dd)) * SEQ + colp) = pk;
      }
    }
  } else {
    const float* bias = (bz == 0) ? bq : bk;
    unsigned short* Out = (bz == 0) ? Qo : Ko;
    const float qs = (bz == 0) ? 0.125f * 1.4426950408889634f : 1.0f;
    const int hh = (n0 + wn) >> 6;
#pragma unroll
    for (int j = 0; j < 4; j++) {
      int nb = n0 + wn + j * 16 + qd * 4;
      f32x4 b4 = *(const f32x4*)(bias + nb);
      int ddb = j * 16 + qd * 4;
#pragma unroll
      for (int i = 0; i < 4; i++) {
        int s = m0 + wm + i * 16 + cl;
        int bb = s >> 11, ss = s & (SEQ - 1);
        f32x4 rl = *(const f32x4*)(rel + ss * DHEAD + ddb);
        float x0 = acc[i][j][0] + b4[0];
        float x1 = acc[i][j][1] + b4[1];
        float x2 = acc[i][j][2] + b4[2];
        float x3 = acc[i][j][3] + b4[3];
        float y0 = (x0 * rl[1] - x1 * rl[0]) * qs;
        float y1 = (x1 * rl[1] + x0 * rl[0]) * qs;
        float y2 = (x2 * rl[3] - x3 * rl[2]) * qs;
        float y3 = (x3 * rl[3] + x2 * rl[2]) * qs;
        u32x2 pk;
        pk[0] = pk2h(y0, y1);
        pk[1] = pk2h(y2, y3);
        *(u32x2*)(Out + (((size_t)(bb * NHEADS + hh)) * SEQ + ss) * DHEAD + ddb) = pk;
      }
    }
  }
}

// ---------------- flash attention (unchanged from R4/R5/R6) ----------------
// Q: [64][2048][64] bf16 pre-scaled by 0.125*log2e; K: [64][2048][64] bf16;
// Vt: [64][64][2048] bf16 (columns permuted, mask-scaled); wm: [4][2048] bf16.
// out: [4][2048][1024] f32.  Softmax inner op = one exp2 per score.
__global__ __launch_bounds__(256, 2) void attn(
    const unsigned short* __restrict__ Q,
    const unsigned short* __restrict__ K,
    const unsigned short* __restrict__ Vt,
    const unsigned short* __restrict__ wmask,
    float* __restrict__ out) {
  __shared__ __align__(16) unsigned short Ks[2][128 * 64];   // [key][d], swizzled
  __shared__ __align__(16) unsigned short Vs[2][64 * 128];   // [d][key'], swizzled

  const int t = threadIdx.x;
  const int lane = t & 63;
  const int w = t >> 6;

  // XCD swizzle: all 16 q-tiles of a bh on one XCD
  const int n = blockIdx.x;          // 0..1023
  const int xcd = n & 7;
  const int li = n >> 3;             // 0..127
  const int bh = xcd * 8 + (li >> 4);
  const int qt = li & 15;

  const int b = bh >> 4, h = bh & 15;
  const int s0 = qt * 128;
  const unsigned short* Qp = Q + (size_t)bh * SEQ * DHEAD;
  const unsigned short* Kp = K + (size_t)bh * SEQ * DHEAD;
  const unsigned short* Vp = Vt + (size_t)bh * DHEAD * SEQ;
  const unsigned short* wmp = wmask + b * SEQ;

  const int cl = lane & 15;
  const int qd = lane >> 4;

  short8 qf[2][2];
#pragma unroll
  for (int mt = 0; mt < 2; mt++)
#pragma unroll
    for (int ks = 0; ks < 2; ks++)
      qf[mt][ks] = *(const short8*)(Qp + (size_t)(s0 + w * 32 + mt * 16 + cl) * DHEAD +
                                    ks * 32 + qd * 8);

  f32x4 ov[2][4];   // [mt][dt], D[d][q]: q=cl, d rows = dt*16+qd*4+r
  f32x4 ovl[2];     // l accumulator (sum_k w_k p_k), all rows identical
#pragma unroll
  for (int mt = 0; mt < 2; mt++) {
    ovl[mt] = (f32x4){0.f, 0.f, 0.f, 0.f};
#pragma unroll
    for (int dt = 0; dt < 4; dt++) ov[mt][dt] = (f32x4){0.f, 0.f, 0.f, 0.f};
  }

  auto stage = [&](int bi, int kt) {
#pragma unroll
    for (int j = 0; j < 4; j++) {
      int r0 = w * 32 + j * 8;
      int r = r0 + (lane >> 3);
      int c = (lane & 7) ^ (r & 7);
      gll16(Kp + (size_t)(kt + r) * DHEAD + c * 8, &Ks[bi][r0 * 64]);
    }
#pragma unroll
    for (int j = 0; j < 4; j++) {
      int r0 = w * 16 + j * 4;
      int r = r0 + (lane >> 4);
      int c = (lane & 15) ^ (r & 7);
      gll16(Vp + (size_t)r * SEQ + kt + c * 8, &Vs[bi][r0 * 128]);
    }
  };

  stage(0, 0);

  for (int it = 0; it < SEQ / 128; it++) {
    const int kt = it * 128;
    const int bi = it & 1;
    __syncthreads();
    if (it + 1 < SEQ / 128) stage(1 - bi, kt + 128);
    const unsigned short* Ksb = &Ks[bi][0];
    const unsigned short* Vsb = &Vs[bi][0];

    // w A-fragment for l-MFMA: keys in P's permuted k-order
    short8 wf[4];
#pragma unroll
    for (int c = 0; c < 4; c++) {
      u32x2 w0 = *(const u32x2*)(wmp + kt + c * 32 + qd * 4);
      u32x2 w1 = *(const u32x2*)(wmp + kt + c * 32 + 16 + qd * 4);
      u32x4 ww = {w0[0], w0[1], w1[0], w1[1]};
      wf[c] = __builtin_bit_cast(short8, ww);
    }

    // ---- scores: D[m=key][n=q] ----
    f32x4 sc[2][8];
#pragma unroll
    for (int mt = 0; mt < 2; mt++)
#pragma unroll
      for (int nt = 0; nt < 8; nt++) sc[mt][nt] = (f32x4){0.f, 0.f, 0.f, 0.f};
#pragma unroll
    for (int ks = 0; ks < 2; ks++) {
#pragma unroll
      for (int nt = 0; nt < 8; nt++) {
        int krow = nt * 16 + cl;
        short8 kf = *(const short8*)(Ksb + krow * 64 +
                                     (((ks * 4 + qd) ^ (krow & 7)) << 3));
        sc[0][nt] = __builtin_amdgcn_mfma_f32_16x16x32_bf16(kf, qf[0][ks], sc[0][nt], 0, 0, 0);
        sc[1][nt] = __builtin_amdgcn_mfma_f32_16x16x32_bf16(kf, qf[1][ks], sc[1][nt], 0, 0, 0);
      }
    }

    // ---- softmax: p = exp2(s) ----
    unsigned pw[2][8][2];
#pragma unroll
    for (int mt = 0; mt < 2; mt++) {
#pragma unroll
      for (int nt = 0; nt < 8; nt++) {
        float p0 = __builtin_amdgcn_exp2f(sc[mt][nt][0]);
        float p1 = __builtin_amdgcn_exp2f(sc[mt][nt][1]);
        float p2 = __builtin_amdgcn_exp2f(sc[mt][nt][2]);
        float p3 = __builtin_amdgcn_exp2f(sc[mt][nt][3]);
        pw[mt][nt][0] = pk2h(p0, p1);
        pw[mt][nt][1] = pk2h(p2, p3);
      }
    }

    // ---- O += V' * P (permuted k-order; V columns pre-permuted to match) ----
#pragma unroll
    for (int c = 0; c < 4; c++) {
      u32x4 bb0 = {pw[0][2 * c][0], pw[0][2 * c][1], pw[0][2 * c + 1][0], pw[0][2 * c + 1][1]};
      u32x4 bb1 = {pw[1][2 * c][0], pw[1][2 * c][1], pw[1][2 * c + 1][0], pw[1][2 * c + 1][1]};
      short8 bf0 = __builtin_bit_cast(short8, bb0);
      short8 bf1 = __builtin_bit_cast(short8, bb1);
      ovl[0] = __builtin_amdgcn_mfma_f32_16x16x32_bf16(wf[c], bf0, ovl[0], 0, 0, 0);
      ovl[1] = __builtin_amdgcn_mfma_f32_16x16x32_bf16(wf[c], bf1, ovl[1], 0, 0, 0);
#pragma unroll
      for (int dt = 0; dt < 4; dt++) {
        int vrow = dt * 16 + cl;
        short8 vf = *(const short8*)(Vsb + vrow * 128 +
                                     (((c * 4 + qd) ^ (vrow & 7)) << 3));
        ov[0][dt] = __builtin_amdgcn_mfma_f32_16x16x32_bf16(vf, bf0, ov[0][dt], 0, 0, 0);
        ov[1][dt] = __builtin_amdgcn_mfma_f32_16x16x32_bf16(vf, bf1, ov[1][dt], 0, 0, 0);
      }
    }
  }

  // ---- epilogue: O[d][q] / l(q) ----
#pragma unroll
  for (int mt = 0; mt < 2; mt++) {
    float rl = 1.0f / ovl[mt][0];
    int s = s0 + w * 32 + mt * 16 + cl;
    float* ob = out + ((size_t)b * SEQ + s) * HD + h * DHEAD;
#pragma unroll
    for (int dt = 0; dt < 4; dt++) {
      f32x4 o;
      o[0] = ov[mt][dt][0] * rl;
      o[1] = ov[mt][dt][1] * rl;
      o[2] = ov[mt][dt][2] * rl;
      o[3] = ov[mt][dt][3] * rl;
      *(f32x4*)(ob + dt * 16 + qd * 4) = o;
    }
  }
}

extern "C" void kernel_launch(void* const* d_in, const int* in_sizes, int n_in,
                              void* d_out, int out_size, void* d_ws, size_t ws_size,
                              hipStream_t stream) {
  const float* hidden = (const float*)d_in[0];
  const float* mask   = (const float*)d_in[1];
  const float* rel    = (const float*)d_in[2];
  const float* Wq     = (const float*)d_in[3];
  const float* bq     = (const float*)d_in[4];
  const float* Wk     = (const float*)d_in[5];
  const float* bk     = (const float*)d_in[6];
  const float* Wv     = (const float*)d_in[7];
  const float* bv     = (const float*)d_in[8];
  float* out = (float*)d_out;

  unsigned short* Xb = (unsigned short*)d_ws;          // 8192*1024
  unsigned short* Wb = Xb + (size_t)MTOT * HD;         // 3*1024*1024
  unsigned short* Qb = Wb + (size_t)3 * HD * HD;       // 8192*1024
  unsigned short* Kb = Qb + (size_t)MTOT * HD;
  unsigned short* Vb = Kb + (size_t)MTOT * HD;
  unsigned short* Wm = Vb + (size_t)MTOT * HD;         // 4*2048

  {
    int n4 = MTOT * HD / 4;
    cvt_bf16<<<n4 / 256, 256, 0, stream>>>(hidden, Xb, n4);
  }
  prep<<<(3 * WQ4 + BATCH * SEQ / 4) / 256, 256, 0, stream>>>(Wq, Wk, Wv, mask, Wb, Wm);
  qkv_gemm<<<dim3(1536), 256, 0, stream>>>(Xb, Wb, bq, bk, bv, rel, mask, Qb, Kb, Vb);
  attn<<<dim3(1024), 256, 0, stream>>>(Qb, Kb, Vb, Wm, out);
}

// Round 8
// 305.962 us; speedup vs baseline: 2.4376x; 2.4376x over previous
//
#include <hip/hip_runtime.h>

typedef __attribute__((ext_vector_type(8))) short short8;
typedef __attribute__((ext_vector_type(4))) float f32x4;
typedef __attribute__((ext_vector_type(4))) unsigned int u32x4;
typedef __attribute__((ext_vector_type(2))) unsigned int u32x2;
typedef __attribute__((ext_vector_type(4))) unsigned short u16x4;

#define NHEADS 16
#define DHEAD 64
#define SEQ 2048
#define BATCH 4
#define HD 1024
#define MTOT 8192  // BATCH*SEQ

// RNE f32->bf16 (cold paths)
static __device__ __forceinline__ unsigned short f2b(float x) {
  unsigned u = __builtin_bit_cast(unsigned, x);
  u += 0x7fffu + ((u >> 16) & 1u);
  return (unsigned short)(u >> 16);
}

// round-half-up pack of two f32 -> bf16x2 (<=0.5 ulp, 4 insts; hot paths)
static __device__ __forceinline__ unsigned pk2h(float lo, float hi) {
  unsigned a = __builtin_bit_cast(unsigned, lo) + 0x8000u;
  unsigned b = __builtin_bit_cast(unsigned, hi) + 0x8000u;
  return (a >> 16) | (b & 0xffff0000u);
}

// async global -> LDS, 16B per lane. LDS dst = wave-uniform base + lane*16.
static __device__ __forceinline__ void gll16(const void* g, void* l) {
  __builtin_amdgcn_global_load_lds(
      (const __attribute__((address_space(1))) unsigned int*)g,
      (__attribute__((address_space(3))) unsigned int*)l, 16, 0, 0);
}

// ---------------- f32 -> bf16 conversion (hidden states) ----------------
__global__ void cvt_bf16(const float* __restrict__ src,
                         unsigned short* __restrict__ dst, int n4) {
  int i = blockIdx.x * blockDim.x + threadIdx.x;
  if (i < n4) {
    f32x4 v = ((const f32x4*)src)[i];
    u16x4 o;
    o[0] = f2b(v[0]); o[1] = f2b(v[1]); o[2] = f2b(v[2]); o[3] = f2b(v[3]);
    ((u16x4*)dst)[i] = o;
  }
}

// ---- combined prep: Wq/Wk/Wv -> bf16, wmask = bf16(exp(mask)) ----
#define WQ4 (HD * HD / 4)   // 262144 vec4s per weight matrix
__global__ void prep(const float* __restrict__ Wq, const float* __restrict__ Wk,
                     const float* __restrict__ Wv, const float* __restrict__ mask,
                     unsigned short* __restrict__ Wb,
                     unsigned short* __restrict__ Wm) {
  int i = blockIdx.x * blockDim.x + threadIdx.x;
  if (i < 3 * WQ4) {
    int rg = i / WQ4;
    int idx = i - rg * WQ4;
    const float* src = (rg == 0) ? Wq : (rg == 1) ? Wk : Wv;
    f32x4 v = ((const f32x4*)src)[idx];
    u16x4 o;
    o[0] = f2b(v[0]); o[1] = f2b(v[1]); o[2] = f2b(v[2]); o[3] = f2b(v[3]);
    ((u16x4*)(Wb + (size_t)rg * HD * HD))[idx] = o;
  } else {
    int j = i - 3 * WQ4;            // 0..2047 vec4s of mask
    f32x4 v = ((const f32x4*)mask)[j];
    u16x4 o;
    o[0] = f2b(__expf(v[0])); o[1] = f2b(__expf(v[1]));
    o[2] = f2b(__expf(v[2])); o[3] = f2b(__expf(v[3]));
    ((u16x4*)Wm)[j] = o;
  }
}

// ---------------- fused QKV GEMM + bias + rotary + scale/mask folds --------
// X: [8192][1024] bf16, W: [3][1024][1024] bf16.
// Q out: rotary * 0.125*log2(e), [B,NH,S,D] bf16.  K out: rotary, same layout.
// V out: transposed [B,NH,D,S'] bf16, columns s PERMUTED within 32-blocks
//        (s = u*16+a*4+r -> s' = a*8+u*4+r) and scaled by exp(mask[b][s]).
// BK=64 k-loop (16 steps) with gather-side XOR swizzle.
// NOTE: no min-waves launch bound — (256,4) forced a 128-VGPR budget and
// spilled acc[4][4] to scratch (R7: VGPR=64, WRITE_SIZE 1.6 GB, 580 us).
__global__ __launch_bounds__(256) void qkv_gemm(
    const unsigned short* __restrict__ X,
    const unsigned short* __restrict__ Wall,
    const float* __restrict__ bq, const float* __restrict__ bk,
    const float* __restrict__ bv,
    const float* __restrict__ rel,          // [2048][64] f32
    const float* __restrict__ mask,         // [4][2048] f32
    unsigned short* __restrict__ Qo,
    unsigned short* __restrict__ Ko,
    unsigned short* __restrict__ Vt) {
  __shared__ __align__(16) unsigned short As[128 * 64];
  __shared__ __align__(16) unsigned short Bs[128 * 64];

  const int t = threadIdx.x;
  const int lane = t & 63;
  const int w = t >> 6;

  // XCD swizzle: pin each W panel (by,bz) to one XCD; bx fastest within panel.
  const int n = blockIdx.x;            // 0..1535
  const int xcd = n & 7;
  const int li = n >> 3;               // 0..191
  const int pp = xcd * 3 + (li >> 6);  // 0..23 W-panel id
  const int bx = li & 63;
  const int by = pp & 7;
  const int bz = pp >> 3;              // 0=Q 1=K 2=V

  const unsigned short* W = Wall + (size_t)bz * HD * HD;
  const int m0 = bx * 128;
  const int n0 = by * 128;

  f32x4 acc[4][4];
  for (int i = 0; i < 4; i++)
    for (int j = 0; j < 4; j++) acc[i][j] = (f32x4){0.f, 0.f, 0.f, 0.f};

  const int wm = (w & 1) * 64;
  const int wn = (w >> 1) * 64;
  const int cl = lane & 15;
  const int qd = lane >> 4;

  for (int k0 = 0; k0 < HD; k0 += 64) {
    __syncthreads();
    // stage 128x64 A and B tiles; lane -> row r0+(lane>>3), gathers global
    // chunk (lane&7)^(r&7) so LDS slot s at row r holds global chunk s^(r&7)
#pragma unroll
    for (int j = 0; j < 4; j++) {
      int r0 = w * 32 + j * 8;
      int r = r0 + (lane >> 3);
      int cg = (((lane & 7) ^ (r & 7)) << 3);
      gll16(X + (size_t)(m0 + r) * HD + k0 + cg, As + r0 * 64);
      gll16(W + (size_t)(n0 + r) * HD + k0 + cg, Bs + r0 * 64);
    }
    __syncthreads();

#pragma unroll
    for (int ks = 0; ks < 2; ks++) {
      const int cc = ks * 4 + qd;
      short8 af[4], bf[4];
#pragma unroll
      for (int i = 0; i < 4; i++) {
        int r = wm + i * 16 + cl;
        af[i] = *(const short8*)(As + r * 64 + ((cc ^ (r & 7)) << 3));
      }
#pragma unroll
      for (int j = 0; j < 4; j++) {
        int r = wn + j * 16 + cl;
        bf[j] = *(const short8*)(Bs + r * 64 + ((cc ^ (r & 7)) << 3));
      }
      if (bz < 2) {
        // transposed: acc[i][j] = D[n(feature)][m(s)]
#pragma unroll
        for (int i = 0; i < 4; i++)
#pragma unroll
          for (int j = 0; j < 4; j++)
            acc[i][j] = __builtin_amdgcn_mfma_f32_16x16x32_bf16(bf[j], af[i],
                                                                acc[i][j], 0, 0, 0);
      } else {
        // normal: acc[i][j] = D[m(s)][n(feature)]
#pragma unroll
        for (int i = 0; i < 4; i++)
#pragma unroll
          for (int j = 0; j < 4; j++)
            acc[i][j] = __builtin_amdgcn_mfma_f32_16x16x32_bf16(af[i], bf[j],
                                                                acc[i][j], 0, 0, 0);
      }
    }
  }

  // ---- epilogue ----
  if (bz == 2) {
    const int hh = (n0 + wn) >> 6;
#pragma unroll
    for (int i = 0; i < 4; i++) {
      int mb = m0 + wm + i * 16 + qd * 4;
      int bb = mb >> 11, ssb = mb & (SEQ - 1);
      f32x4 mk = *(const f32x4*)(mask + bb * SEQ + ssb);
      f32x4 w4;
#pragma unroll
      for (int r = 0; r < 4; r++) w4[r] = __expf(mk[r]);
      int colp = (ssb & ~31) | ((ssb & 12) << 1) | (((ssb >> 4) & 1) << 2);
#pragma unroll
      for (int j = 0; j < 4; j++) {
        int nn = n0 + wn + j * 16 + cl;
        int dd = j * 16 + cl;
        float bn = bv[nn];
        u32x2 pk;
        pk[0] = pk2h((acc[i][j][0] + bn) * w4[0], (acc[i][j][1] + bn) * w4[1]);
        pk[1] = pk2h((acc[i][j][2] + bn) * w4[2], (acc[i][j][3] + bn) * w4[3]);
        *(u32x2*)(Vt + ((size_t)((bb * NHEADS + hh) * DHEAD + dd)) * SEQ + colp) = pk;
      }
    }
  } else {
    const float* bias = (bz == 0) ? bq : bk;
    unsigned short* Out = (bz == 0) ? Qo : Ko;
    const float qs = (bz == 0) ? 0.125f * 1.4426950408889634f : 1.0f;
    const int hh = (n0 + wn) >> 6;
#pragma unroll
    for (int j = 0; j < 4; j++) {
      int nb = n0 + wn + j * 16 + qd * 4;
      f32x4 b4 = *(const f32x4*)(bias + nb);
      int ddb = j * 16 + qd * 4;
#pragma unroll
      for (int i = 0; i < 4; i++) {
        int s = m0 + wm + i * 16 + cl;
        int bb = s >> 11, ss = s & (SEQ - 1);
        f32x4 rl = *(const f32x4*)(rel + ss * DHEAD + ddb);
        float x0 = acc[i][j][0] + b4[0];
        float x1 = acc[i][j][1] + b4[1];
        float x2 = acc[i][j][2] + b4[2];
        float x3 = acc[i][j][3] + b4[3];
        float y0 = (x0 * rl[1] - x1 * rl[0]) * qs;
        float y1 = (x1 * rl[1] + x0 * rl[0]) * qs;
        float y2 = (x2 * rl[3] - x3 * rl[2]) * qs;
        float y3 = (x3 * rl[3] + x2 * rl[2]) * qs;
        u32x2 pk;
        pk[0] = pk2h(y0, y1);
        pk[1] = pk2h(y2, y3);
        *(u32x2*)(Out + (((size_t)(bb * NHEADS + hh)) * SEQ + ss) * DHEAD + ddb) = pk;
      }
    }
  }
}

// ---------------- flash attention (unchanged from R4/R5/R6) ----------------
// Q: [64][2048][64] bf16 pre-scaled by 0.125*log2e; K: [64][2048][64] bf16;
// Vt: [64][64][2048] bf16 (columns permuted, mask-scaled); wm: [4][2048] bf16.
// out: [4][2048][1024] f32.  Softmax inner op = one exp2 per score.
__global__ __launch_bounds__(256, 2) void attn(
    const unsigned short* __restrict__ Q,
    const unsigned short* __restrict__ K,
    const unsigned short* __restrict__ Vt,
    const unsigned short* __restrict__ wmask,
    float* __restrict__ out) {
  __shared__ __align__(16) unsigned short Ks[2][128 * 64];   // [key][d], swizzled
  __shared__ __align__(16) unsigned short Vs[2][64 * 128];   // [d][key'], swizzled

  const int t = threadIdx.x;
  const int lane = t & 63;
  const int w = t >> 6;

  // XCD swizzle: all 16 q-tiles of a bh on one XCD
  const int n = blockIdx.x;          // 0..1023
  const int xcd = n & 7;
  const int li = n >> 3;             // 0..127
  const int bh = xcd * 8 + (li >> 4);
  const int qt = li & 15;

  const int b = bh >> 4, h = bh & 15;
  const int s0 = qt * 128;
  const unsigned short* Qp = Q + (size_t)bh * SEQ * DHEAD;
  const unsigned short* Kp = K + (size_t)bh * SEQ * DHEAD;
  const unsigned short* Vp = Vt + (size_t)bh * DHEAD * SEQ;
  const unsigned short* wmp = wmask + b * SEQ;

  const int cl = lane & 15;
  const int qd = lane >> 4;

  short8 qf[2][2];
#pragma unroll
  for (int mt = 0; mt < 2; mt++)
#pragma unroll
    for (int ks = 0; ks < 2; ks++)
      qf[mt][ks] = *(const short8*)(Qp + (size_t)(s0 + w * 32 + mt * 16 + cl) * DHEAD +
                                    ks * 32 + qd * 8);

  f32x4 ov[2][4];   // [mt][dt], D[d][q]: q=cl, d rows = dt*16+qd*4+r
  f32x4 ovl[2];     // l accumulator (sum_k w_k p_k), all rows identical
#pragma unroll
  for (int mt = 0; mt < 2; mt++) {
    ovl[mt] = (f32x4){0.f, 0.f, 0.f, 0.f};
#pragma unroll
    for (int dt = 0; dt < 4; dt++) ov[mt][dt] = (f32x4){0.f, 0.f, 0.f, 0.f};
  }

  auto stage = [&](int bi, int kt) {
#pragma unroll
    for (int j = 0; j < 4; j++) {
      int r0 = w * 32 + j * 8;
      int r = r0 + (lane >> 3);
      int c = (lane & 7) ^ (r & 7);
      gll16(Kp + (size_t)(kt + r) * DHEAD + c * 8, &Ks[bi][r0 * 64]);
    }
#pragma unroll
    for (int j = 0; j < 4; j++) {
      int r0 = w * 16 + j * 4;
      int r = r0 + (lane >> 4);
      int c = (lane & 15) ^ (r & 7);
      gll16(Vp + (size_t)r * SEQ + kt + c * 8, &Vs[bi][r0 * 128]);
    }
  };

  stage(0, 0);

  for (int it = 0; it < SEQ / 128; it++) {
    const int kt = it * 128;
    const int bi = it & 1;
    __syncthreads();
    if (it + 1 < SEQ / 128) stage(1 - bi, kt + 128);
    const unsigned short* Ksb = &Ks[bi][0];
    const unsigned short* Vsb = &Vs[bi][0];

    // w A-fragment for l-MFMA: keys in P's permuted k-order
    short8 wf[4];
#pragma unroll
    for (int c = 0; c < 4; c++) {
      u32x2 w0 = *(const u32x2*)(wmp + kt + c * 32 + qd * 4);
      u32x2 w1 = *(const u32x2*)(wmp + kt + c * 32 + 16 + qd * 4);
      u32x4 ww = {w0[0], w0[1], w1[0], w1[1]};
      wf[c] = __builtin_bit_cast(short8, ww);
    }

    // ---- scores: D[m=key][n=q] ----
    f32x4 sc[2][8];
#pragma unroll
    for (int mt = 0; mt < 2; mt++)
#pragma unroll
      for (int nt = 0; nt < 8; nt++) sc[mt][nt] = (f32x4){0.f, 0.f, 0.f, 0.f};
#pragma unroll
    for (int ks = 0; ks < 2; ks++) {
#pragma unroll
      for (int nt = 0; nt < 8; nt++) {
        int krow = nt * 16 + cl;
        short8 kf = *(const short8*)(Ksb + krow * 64 +
                                     (((ks * 4 + qd) ^ (krow & 7)) << 3));
        sc[0][nt] = __builtin_amdgcn_mfma_f32_16x16x32_bf16(kf, qf[0][ks], sc[0][nt], 0, 0, 0);
        sc[1][nt] = __builtin_amdgcn_mfma_f32_16x16x32_bf16(kf, qf[1][ks], sc[1][nt], 0, 0, 0);
      }
    }

    // ---- softmax: p = exp2(s) ----
    unsigned pw[2][8][2];
#pragma unroll
    for (int mt = 0; mt < 2; mt++) {
#pragma unroll
      for (int nt = 0; nt < 8; nt++) {
        float p0 = __builtin_amdgcn_exp2f(sc[mt][nt][0]);
        float p1 = __builtin_amdgcn_exp2f(sc[mt][nt][1]);
        float p2 = __builtin_amdgcn_exp2f(sc[mt][nt][2]);
        float p3 = __builtin_amdgcn_exp2f(sc[mt][nt][3]);
        pw[mt][nt][0] = pk2h(p0, p1);
        pw[mt][nt][1] = pk2h(p2, p3);
      }
    }

    // ---- O += V' * P (permuted k-order; V columns pre-permuted to match) ----
#pragma unroll
    for (int c = 0; c < 4; c++) {
      u32x4 bb0 = {pw[0][2 * c][0], pw[0][2 * c][1], pw[0][2 * c + 1][0], pw[0][2 * c + 1][1]};
      u32x4 bb1 = {pw[1][2 * c][0], pw[1][2 * c][1], pw[1][2 * c + 1][0], pw[1][2 * c + 1][1]};
      short8 bf0 = __builtin_bit_cast(short8, bb0);
      short8 bf1 = __builtin_bit_cast(short8, bb1);
      ovl[0] = __builtin_amdgcn_mfma_f32_16x16x32_bf16(wf[c], bf0, ovl[0], 0, 0, 0);
      ovl[1] = __builtin_amdgcn_mfma_f32_16x16x32_bf16(wf[c], bf1, ovl[1], 0, 0, 0);
#pragma unroll
      for (int dt = 0; dt < 4; dt++) {
        int vrow = dt * 16 + cl;
        short8 vf = *(const short8*)(Vsb + vrow * 128 +
                                     (((c * 4 + qd) ^ (vrow & 7)) << 3));
        ov[0][dt] = __builtin_amdgcn_mfma_f32_16x16x32_bf16(vf, bf0, ov[0][dt], 0, 0, 0);
        ov[1][dt] = __builtin_amdgcn_mfma_f32_16x16x32_bf16(vf, bf1, ov[1][dt], 0, 0, 0);
      }
    }
  }

  // ---- epilogue: O[d][q] / l(q) ----
#pragma unroll
  for (int mt = 0; mt < 2; mt++) {
    float rl = 1.0f / ovl[mt][0];
    int s = s0 + w * 32 + mt * 16 + cl;
    float* ob = out + ((size_t)b * SEQ + s) * HD + h * DHEAD;
#pragma unroll
    for (int dt = 0; dt < 4; dt++) {
      f32x4 o;
      o[0] = ov[mt][dt][0] * rl;
      o[1] = ov[mt][dt][1] * rl;
      o[2] = ov[mt][dt][2] * rl;
      o[3] = ov[mt][dt][3] * rl;
      *(f32x4*)(ob + dt * 16 + qd * 4) = o;
    }
  }
}

extern "C" void kernel_launch(void* const* d_in, const int* in_sizes, int n_in,
                              void* d_out, int out_size, void* d_ws, size_t ws_size,
                              hipStream_t stream) {
  const float* hidden = (const float*)d_in[0];
  const float* mask   = (const float*)d_in[1];
  const float* rel    = (const float*)d_in[2];
  const float* Wq     = (const float*)d_in[3];
  const float* bq     = (const float*)d_in[4];
  const float* Wk     = (const float*)d_in[5];
  const float* bk     = (const float*)d_in[6];
  const float* Wv     = (const float*)d_in[7];
  const float* bv     = (const float*)d_in[8];
  float* out = (float*)d_out;

  unsigned short* Xb = (unsigned short*)d_ws;          // 8192*1024
  unsigned short* Wb = Xb + (size_t)MTOT * HD;         // 3*1024*1024
  unsigned short* Qb = Wb + (size_t)3 * HD * HD;       // 8192*1024
  unsigned short* Kb = Qb + (size_t)MTOT * HD;
  unsigned short* Vb = Kb + (size_t)MTOT * HD;
  unsigned short* Wm = Vb + (size_t)MTOT * HD;         // 4*2048

  {
    int n4 = MTOT * HD / 4;
    cvt_bf16<<<n4 / 256, 256, 0, stream>>>(hidden, Xb, n4);
  }
  prep<<<(3 * WQ4 + BATCH * SEQ / 4) / 256, 256, 0, stream>>>(Wq, Wk, Wv, mask, Wb, Wm);
  qkv_gemm<<<dim3(1536), 256, 0, stream>>>(Xb, Wb, bq, bk, bv, rel, mask, Qb, Kb, Vb);
  attn<<<dim3(1024), 256, 0, stream>>>(Qb, Kb, Vb, Wm, out);
}